// Round 5
// baseline (182.057 us; speedup 1.0000x reference)
//
#include <hip/hip_runtime.h>

// Problem constants (from reference):
constexpr int kB    = 32;
constexpr int kTin  = 512;
constexpr int kTout = 2048;
constexpr int kA    = 384;   // ADIM
constexpr int kC4   = kA / 4; // 96 float4 per output row

constexpr int kBlocksPerBatch = 16;
constexpr int kRowsPerBlock   = kTout / kBlocksPerBatch; // 128

// Native clang vector (HIP float4 is a class; nontemporal builtins reject it).
typedef float v4f __attribute__((ext_vector_type(4)));

// ---------------------------------------------------------------------------
// Kernel A: length-regulation index computation (tiny, 32 blocks).
// One block per batch, 512 threads. Masked-duration cumsum in LDS, then
// searchsorted(cum, t, 'right') per output frame -> idx[b,t] (or -1 padded).
// Identical to the R1 version that passed.
// ---------------------------------------------------------------------------
__global__ __launch_bounds__(kTin) void lr_index_kernel(
    const int* __restrict__ durations,      // [B, T_IN]
    const int* __restrict__ input_lengths,  // [B]
    int* __restrict__ idx_out)              // [B, T_OUT]
{
    __shared__ int cum[kTin];
    const int b = blockIdx.x;
    const int t = threadIdx.x;
    const int len = input_lengths[b];
    const bool valid = t < len;
    int dval = valid ? durations[b * kTin + t] : 0;
    int total = 0;
    // Up to 2 passes: reference refills d with ones (at valid positions) if
    // the masked sum is zero. Branch on `total` is block-uniform.
    for (int pass = 0; pass < 2; ++pass) {
        __syncthreads();
        cum[t] = dval;
        __syncthreads();
        for (int off = 1; off < kTin; off <<= 1) {
            int add = (t >= off) ? cum[t - off] : 0;
            __syncthreads();
            cum[t] += add;
            __syncthreads();
        }
        total = cum[kTin - 1];
        if (total != 0) break;
        dval = valid ? 1 : 0;
    }
    // Guarded binary search (up to 10 iters: 513 outcomes — see R3 bug).
    for (int k = 0; k < kTout / kTin; ++k) {
        const int to = t + k * kTin;
        int lo = 0, hi = kTin;
        while (lo < hi) {
            const int mid = (lo + hi) >> 1;
            if (cum[mid] <= to) lo = mid + 1; else hi = mid;
        }
        int idx = (lo < kTin) ? lo : (kTin - 1);
        idx_out[b * kTout + to] = (to < total) ? idx : -1;
    }
}

// ---------------------------------------------------------------------------
// Kernel B: pure-streaming gather + pitch/energy embed + bias. No LDS, no
// barriers — memory stream starts at instruction 0.
//  - fixed per-batch slices (b = blockIdx>>4) keep the hs gather L2-local
//  - weights register-resident (c4 = tid % 96 fixed per thread)
//  - non-temporal LOADS for read-once pitch/energy targets (don't pollute L2)
//  - non-temporal STORES for the 100 MB out-stream (keep L2 for hs)
// ---------------------------------------------------------------------------
__global__ __launch_bounds__(384) void va_embed_kernel(
    const float* __restrict__ hs,         // [B, T_IN, ADIM]
    const int*   __restrict__ idx,        // [B, T_OUT]
    const v4f*   __restrict__ pitch_t,    // [B*T_OUT] (PDIM=4 packed)
    const float* __restrict__ energy_t,   // [B*T_OUT] (EDIM=1)
    const v4f*   __restrict__ pitch_w,    // [ADIM] rows of 4
    const float* __restrict__ pitch_b,    // [ADIM]
    const float* __restrict__ energy_w,   // [ADIM]
    const float* __restrict__ energy_b,   // [ADIM]
    v4f*         __restrict__ out)        // [B*T_OUT*kC4]
{
    const int tid = threadIdx.x;
    const int c4  = tid % kC4;   // fixed channel quad
    const int sub = tid / kC4;   // 0..3 row slot
    const int a0  = c4 * 4;

    const int b   = blockIdx.x >> 4;     // batch
    const int blk = blockIdx.x & 15;     // slice within batch

    // Register-resident weights (loaded once, L1-served).
    const v4f w0 = pitch_w[a0];
    const v4f w1 = pitch_w[a0 + 1];
    const v4f w2 = pitch_w[a0 + 2];
    const v4f w3 = pitch_w[a0 + 3];
    v4f ew;
    ew.x = energy_w[a0];     ew.y = energy_w[a0 + 1];
    ew.z = energy_w[a0 + 2]; ew.w = energy_w[a0 + 3];
    v4f bias;
    bias.x = pitch_b[a0]     + energy_b[a0];
    bias.y = pitch_b[a0 + 1] + energy_b[a0 + 1];
    bias.z = pitch_b[a0 + 2] + energy_b[a0 + 2];
    bias.w = pitch_b[a0 + 3] + energy_b[a0 + 3];

    const int row0     = blk * kRowsPerBlock;
    const int hs_base  = b * kTin * kA;   // < 2^23, 32-bit safe
    const int row_base = b * kTout;

    for (int r = sub; r < kRowsPerBlock; r += 4) {
        const int row = row_base + row0 + r;    // < 65536

        const int sidx = idx[row];              // broadcast across 96 lanes
        v4f h = (v4f)(0.f);
        if (sidx >= 0)
            h = *(const v4f*)(hs + hs_base + sidx * kA + a0);

        const v4f  pt = __builtin_nontemporal_load(&pitch_t[row]);
        const float e = __builtin_nontemporal_load(&energy_t[row]);
        v4f o;
        o.x = h.x + pt.x * w0.x + pt.y * w0.y + pt.z * w0.z + pt.w * w0.w + e * ew.x + bias.x;
        o.y = h.y + pt.x * w1.x + pt.y * w1.y + pt.z * w1.z + pt.w * w1.w + e * ew.y + bias.y;
        o.z = h.z + pt.x * w2.x + pt.y * w2.y + pt.z * w2.z + pt.w * w2.w + e * ew.z + bias.z;
        o.w = h.w + pt.x * w3.x + pt.y * w3.y + pt.z * w3.z + pt.w * w3.w + e * ew.w + bias.w;
        __builtin_nontemporal_store(o, &out[row * kC4 + c4]);
    }
}

extern "C" void kernel_launch(void* const* d_in, const int* in_sizes, int n_in,
                              void* d_out, int out_size, void* d_ws, size_t ws_size,
                              hipStream_t stream) {
    // setup_inputs() order:
    // 0 hs[32,512,384] f32 | 1 durations[32,512] int | 2 input_lengths[32] int
    // 3 pitch_target[32,2048,4] f32 | 4 energy_target[32,2048,1] f32
    // 5 duration_mask (unused) | 6 variance_mask (unused)
    // 7 pitch_w[384,4] f32 | 8 pitch_b[384] f32 | 9 energy_w[384,1] f32 | 10 energy_b[384] f32
    const float* hs            = (const float*)d_in[0];
    const int*   durations     = (const int*)d_in[1];
    const int*   input_lengths = (const int*)d_in[2];
    const float* pitch_t       = (const float*)d_in[3];
    const float* energy_t      = (const float*)d_in[4];
    const float* pitch_w       = (const float*)d_in[7];
    const float* pitch_b       = (const float*)d_in[8];
    const float* energy_w      = (const float*)d_in[9];
    const float* energy_b      = (const float*)d_in[10];
    float* out = (float*)d_out;
    int*   idx = (int*)d_ws;   // 32*2048 ints = 256 KB scratch

    lr_index_kernel<<<kB, kTin, 0, stream>>>(durations, input_lengths, idx);
    va_embed_kernel<<<kB * kBlocksPerBatch, 384, 0, stream>>>(
        hs, idx,
        (const v4f*)pitch_t, energy_t,
        (const v4f*)pitch_w, pitch_b, energy_w, energy_b,
        (v4f*)out);
}

// Round 6
// 178.704 us; speedup vs baseline: 1.0188x; 1.0188x over previous
//
#include <hip/hip_runtime.h>

// Problem constants (from reference):
constexpr int kB    = 32;
constexpr int kTin  = 512;
constexpr int kTout = 2048;
constexpr int kA    = 384;   // ADIM
constexpr int kC4   = kA / 4; // 96 float4 per output row

constexpr int kBlocksPerBatch = 16;
constexpr int kRowsPerBlock   = kTout / kBlocksPerBatch; // 128

typedef float v4f __attribute__((ext_vector_type(4)));

// ---------------------------------------------------------------------------
// Kernel A: length-regulation index computation (tiny, 32 blocks).
// One block per batch, 512 threads. Masked-duration cumsum in LDS, then
// searchsorted(cum, t, 'right') per output frame -> idx[b,t] (or -1 padded).
// ---------------------------------------------------------------------------
__global__ __launch_bounds__(kTin) void lr_index_kernel(
    const int* __restrict__ durations,      // [B, T_IN]
    const int* __restrict__ input_lengths,  // [B]
    int* __restrict__ idx_out)              // [B, T_OUT]
{
    __shared__ int cum[kTin];
    const int b = blockIdx.x;
    const int t = threadIdx.x;
    const int len = input_lengths[b];
    const bool valid = t < len;
    int dval = valid ? durations[b * kTin + t] : 0;
    int total = 0;
    // Up to 2 passes: reference refills d with ones (at valid positions) if
    // the masked sum is zero. Branch on `total` is block-uniform.
    for (int pass = 0; pass < 2; ++pass) {
        __syncthreads();
        cum[t] = dval;
        __syncthreads();
        for (int off = 1; off < kTin; off <<= 1) {
            int add = (t >= off) ? cum[t - off] : 0;
            __syncthreads();
            cum[t] += add;
            __syncthreads();
        }
        total = cum[kTin - 1];
        if (total != 0) break;
        dval = valid ? 1 : 0;
    }
    // Guarded binary search (up to 10 iters: 513 outcomes — see R3 bug).
    for (int k = 0; k < kTout / kTin; ++k) {
        const int to = t + k * kTin;
        int lo = 0, hi = kTin;
        while (lo < hi) {
            const int mid = (lo + hi) >> 1;
            if (cum[mid] <= to) lo = mid + 1; else hi = mid;
        }
        int idx = (lo < kTin) ? lo : (kTin - 1);
        idx_out[b * kTout + to] = (to < total) ? idx : -1;
    }
}

// ---------------------------------------------------------------------------
// Kernel B: pure-streaming gather + pitch/energy embed + bias. No LDS, no
// barriers. PLAIN loads/stores throughout:
//   R4/R5 post-mortem — the harness re-poisons d_out (100 MB, 0xAA) before
//   every timed launch, leaving dirty lines in L2. Normal stores overwrite
//   them in-cache; NONTEMPORAL stores bypass L2 and force the poison
//   writeback + the nt write to HBM (~+100 MB ≈ +16-24 µs, measured
//   158→177/182). Do NOT reintroduce __builtin_nontemporal_* here.
// ---------------------------------------------------------------------------
__global__ __launch_bounds__(384) void va_embed_kernel(
    const float* __restrict__ hs,         // [B, T_IN, ADIM]
    const int*   __restrict__ idx,        // [B, T_OUT]
    const v4f*   __restrict__ pitch_t,    // [B*T_OUT] (PDIM=4 packed)
    const float* __restrict__ energy_t,   // [B*T_OUT] (EDIM=1)
    const v4f*   __restrict__ pitch_w,    // [ADIM] rows of 4
    const float* __restrict__ pitch_b,    // [ADIM]
    const float* __restrict__ energy_w,   // [ADIM]
    const float* __restrict__ energy_b,   // [ADIM]
    v4f*         __restrict__ out)        // [B*T_OUT*kC4]
{
    const int tid = threadIdx.x;
    const int c4  = tid % kC4;   // fixed channel quad
    const int sub = tid / kC4;   // 0..3 row slot
    const int a0  = c4 * 4;

    const int b   = blockIdx.x >> 4;     // batch
    const int blk = blockIdx.x & 15;     // slice within batch

    // Register-resident weights (loaded once, L1-served).
    const v4f w0 = pitch_w[a0];
    const v4f w1 = pitch_w[a0 + 1];
    const v4f w2 = pitch_w[a0 + 2];
    const v4f w3 = pitch_w[a0 + 3];
    v4f ew;
    ew.x = energy_w[a0];     ew.y = energy_w[a0 + 1];
    ew.z = energy_w[a0 + 2]; ew.w = energy_w[a0 + 3];
    v4f bias;
    bias.x = pitch_b[a0]     + energy_b[a0];
    bias.y = pitch_b[a0 + 1] + energy_b[a0 + 1];
    bias.z = pitch_b[a0 + 2] + energy_b[a0 + 2];
    bias.w = pitch_b[a0 + 3] + energy_b[a0 + 3];

    const int row0     = blk * kRowsPerBlock;
    const int hs_base  = b * kTin * kA;   // < 2^23, 32-bit safe
    const int row_base = b * kTout;

    for (int r = sub; r < kRowsPerBlock; r += 4) {
        const int row = row_base + row0 + r;    // < 65536

        const int sidx = idx[row];              // broadcast across 96 lanes
        v4f h = (v4f)(0.f);
        if (sidx >= 0)
            h = *(const v4f*)(hs + hs_base + sidx * kA + a0);

        const v4f  pt = pitch_t[row];
        const float e = energy_t[row];
        v4f o;
        o.x = h.x + pt.x * w0.x + pt.y * w0.y + pt.z * w0.z + pt.w * w0.w + e * ew.x + bias.x;
        o.y = h.y + pt.x * w1.x + pt.y * w1.y + pt.z * w1.z + pt.w * w1.w + e * ew.y + bias.y;
        o.z = h.z + pt.x * w2.x + pt.y * w2.y + pt.z * w2.z + pt.w * w2.w + e * ew.z + bias.z;
        o.w = h.w + pt.x * w3.x + pt.y * w3.y + pt.z * w3.z + pt.w * w3.w + e * ew.w + bias.w;
        out[row * kC4 + c4] = o;
    }
}

extern "C" void kernel_launch(void* const* d_in, const int* in_sizes, int n_in,
                              void* d_out, int out_size, void* d_ws, size_t ws_size,
                              hipStream_t stream) {
    // setup_inputs() order:
    // 0 hs[32,512,384] f32 | 1 durations[32,512] int | 2 input_lengths[32] int
    // 3 pitch_target[32,2048,4] f32 | 4 energy_target[32,2048,1] f32
    // 5 duration_mask (unused) | 6 variance_mask (unused)
    // 7 pitch_w[384,4] f32 | 8 pitch_b[384] f32 | 9 energy_w[384,1] f32 | 10 energy_b[384] f32
    const float* hs            = (const float*)d_in[0];
    const int*   durations     = (const int*)d_in[1];
    const int*   input_lengths = (const int*)d_in[2];
    const float* pitch_t       = (const float*)d_in[3];
    const float* energy_t      = (const float*)d_in[4];
    const float* pitch_w       = (const float*)d_in[7];
    const float* pitch_b       = (const float*)d_in[8];
    const float* energy_w      = (const float*)d_in[9];
    const float* energy_b      = (const float*)d_in[10];
    float* out = (float*)d_out;
    int*   idx = (int*)d_ws;   // 32*2048 ints = 256 KB scratch

    lr_index_kernel<<<kB, kTin, 0, stream>>>(durations, input_lengths, idx);
    va_embed_kernel<<<kB * kBlocksPerBatch, 384, 0, stream>>>(
        hs, idx,
        (const v4f*)pitch_t, energy_t,
        (const v4f*)pitch_w, pitch_b, energy_w, energy_b,
        (v4f*)out);
}